// Round 12
// baseline (1026.522 us; speedup 1.0000x reference)
//
#include <hip/hip_runtime.h>

typedef _Float16 h8 __attribute__((ext_vector_type(8)));
typedef float    f4 __attribute__((ext_vector_type(4)));
typedef unsigned int u4 __attribute__((ext_vector_type(4)));

#define IMG_N 8
#define IMG_H 512
#define IMG_W 512
#define P_CNT 256
#define PSFN  64
#define SENS  1024

// fp16 tiles, parity-planar (halves):
// (0,0)@0 4096, (0,1)@4096 4096, (1,0)@8192 4032, (1,1)@12224 4032
#define TILE_HALVES 16256
#define TILES_BYTES ((size_t)IMG_N * P_CNT * TILE_HALVES * 2)   // 66,584,576

// Kfrag[p][cls][g][w]: h8 entry w = {K_cls[e = w+j-32][g]}_{j=0..7}, 16B-aligned
// by duplication.  w = t0 = 8q - m + (U0-16ut) + 32 in [0,89).
#define KW     90
#define KWB    (KW * 16)             // bytes per g-row
#define KFRAG_PER_P (4 * 33 * KW)    // 11880 entries

// BT[97 cols][40 r] fp16, col = c+32, zero-padded outside c in [0,32).
#define BT_COLS   97
#define BT_HALVES (BT_COLS * 40)

// ---------------- prep: build Kfrag fragment table (4 blocks per region) ---
__global__ __launch_bounds__(256) void svconv_prep(
    const float* __restrict__ psf, u4* __restrict__ kfrag)
{
    __shared__ float ps[PSFN * PSFN];
    __shared__ float Kc[4 * 33 * 33];      // Kc[cls][e][g], zero if invalid
    const int p = blockIdx.x >> 2, q4 = blockIdx.x & 3, tid = threadIdx.x;

    const float4* pp = (const float4*)(psf + (size_t)p * PSFN * PSFN);
    float4* pd = (float4*)ps;
    for (int i = tid; i < PSFN * PSFN / 4; i += 256) pd[i] = pp[i];
    __syncthreads();

    // K_cls[e][g] = Wp[a=2e-1+pi][b=2g-1+pj], Wp = 2x2-aggregated psf
    for (int idx = tid; idx < 4 * 33 * 33; idx += 256) {
        const int g = idx % 33, e = (idx / 33) % 33, cls = idx / 1089;
        const int pi = cls >> 1, pj = cls & 1;
        const int E = pi ? 32 : 33;
        float sv = 0.f;
        if (e < E) {
            const int a = 2 * e - 1 + pi, b = 2 * g - 1 + pj;
            #pragma unroll
            for (int du = 0; du < 2; ++du) {
                const int x = a + du;
                if ((unsigned)x < 64u) {
                    #pragma unroll
                    for (int dv = 0; dv < 2; ++dv) {
                        const int y = b + dv;
                        if ((unsigned)y < 64u) sv += ps[x * 64 + y];
                    }
                }
            }
        }
        Kc[idx] = sv;
    }
    __syncthreads();

    u4* kout = kfrag + (size_t)p * KFRAG_PER_P;
    for (int i2 = tid; i2 < KFRAG_PER_P / 4; i2 += 256) {
        const int idx = q4 * (KFRAG_PER_P / 4) + i2;
        const int w = idx % KW;
        const int g = (idx / KW) % 33;
        const int cls = idx / (KW * 33);
        h8 hv;
        #pragma unroll
        for (int j = 0; j < 8; ++j) {
            const int e = w + j - 32;
            const float v = ((unsigned)e < 33u) ? Kc[cls * 1089 + e * 33 + g] : 0.f;
            hv[j] = (_Float16)v;
        }
        kout[idx] = __builtin_bit_cast(u4, hv);
    }
}

// ---------------- main: MFMA, global A (R10 loop), LDS B; 8 blocks/CU ------
// R11 lesson: full unroll + ping-pong spilled acc to scratch (WRITE 460 MB).
// Keep the R10 body (proven 94 us, VGPR=64, no spill); raise occupancy via
// __launch_bounds__(256, 8): VGPR budget 512/8 = 64 = R10's natural count.
__global__ __launch_bounds__(256, 8) void svconv_main(
    const float* __restrict__ imgs, const u4* __restrict__ kfrag,
    _Float16* __restrict__ tiles)
{
    __shared__ __align__(16) _Float16 BT[BT_HALVES];   // 7760 B

    const int bid = blockIdx.x;
    const int n = bid >> 8, p = bid & 255;
    const int bh = p & 15, bw = p >> 4;
    const int tid = threadIdx.x;
    const int wv = tid >> 6, lane = tid & 63;
    const int m = lane & 15, q = lane >> 4;

    for (int i = tid; i < BT_HALVES; i += 256) BT[i] = (_Float16)0.f;
    __syncthreads();
    {
        const int r0 = tid >> 5, c = tid & 31;
        const float* src = imgs + ((size_t)n * IMG_H + bh * 32) * IMG_W + bw * 32;
        for (int r = r0; r < 32; r += 8)
            BT[(c + 32) * 40 + r] = (_Float16)src[r * IMG_W + c];
    }
    __syncthreads();

    const int cls = wv, pi = cls >> 1, pj = cls & 1;
    const int U0 = pi ? 31 : 32;
    const char* btc = (const char*)BT + pj * 80;   // pj: c = v+g-32+pj

    int boff[4];
    #pragma unroll
    for (int vt = 0; vt < 4; ++vt) boff[vt] = (16 * vt + m) * 80 + q * 16;

    const char* ka[4];
    {
        const char* base = (const char*)(kfrag + (size_t)p * KFRAG_PER_P
                                         + cls * 33 * KW);
        #pragma unroll
        for (int ut = 0; ut < 4; ++ut) {
            const int t0 = 8 * q - m + (U0 - 16 * ut) + 32;   // in [0,88]
            ka[ut] = base + t0 * 16;
        }
    }

    f4 acc[4][4];
    #pragma unroll
    for (int ut = 0; ut < 4; ++ut)
        #pragma unroll
        for (int vt = 0; vt < 4; ++vt) acc[ut][vt] = (f4){0.f, 0.f, 0.f, 0.f};

    #pragma unroll 3
    for (int g = 0; g < 33; ++g) {
        h8 A[4];
        #pragma unroll
        for (int ut = 0; ut < 4; ++ut)
            A[ut] = __builtin_bit_cast(h8, *(const u4*)(ka[ut] + g * KWB));
        h8 B[4];
        #pragma unroll
        for (int vt = 0; vt < 4; ++vt)
            B[vt] = *(const h8*)(btc + boff[vt] + g * 80);
        #pragma unroll
        for (int ut = 0; ut < 4; ++ut)
            #pragma unroll
            for (int vt = 0; vt < 4; ++vt)
                acc[ut][vt] = __builtin_amdgcn_mfma_f32_16x16x32_f16(
                    A[ut], B[vt], acc[ut][vt], 0, 0, 0);
    }

    // epilogue: C/D col=lane&15 (v), row=quad*4+reg (u); fp16 planar tile
    _Float16* tile = tiles + (size_t)(n * P_CNT + p) * TILE_HALVES;
    const int plane = pi ? (8192 + pj * 4032) : (pj * 4096);
    #pragma unroll
    for (int ut = 0; ut < 4; ++ut) {
        #pragma unroll
        for (int reg = 0; reg < 4; ++reg) {
            const int u = 16 * ut + 4 * q + reg;
            if (pi == 0 || u < 63) {                 // pi=1 u=63 -> i=127 discard
                _Float16* rp = tile + plane + u * 64 + m;
                #pragma unroll
                for (int vt = 0; vt < 4; ++vt)
                    rp[16 * vt] = (_Float16)acc[ut][vt][reg];
            }
        }
    }
}

// ---------------- gather: LDS-staged tile rows, XCD-swizzled ---------------
// Ls[k3][bww][pj][64] halves, k3 = bh - bhlo in [0,3); + 64-half zero slot.
#define LROWS 96
#define ZOFF  (LROWS * 64)   // 6144

__global__ __launch_bounds__(256) void svconv_gather(
    const _Float16* __restrict__ tiles, float* __restrict__ out)
{
    __shared__ __align__(16) _Float16 Ls[ZOFF + 64];

    // XCD swizzle: consecutive blocks on one XCD get one n and consecutive x
    // -> per-XCD tile working set ~8.3 MB, adjacent x share bh-bands (L2 reuse)
    const int bid = blockIdx.x;
    const int n = bid & 7, x = bid >> 3;
    const int tid = threadIdx.x;

    int bhlo = (x + 288) / 48 - 10; if (bhlo < 0) bhlo = 0;
    const int bhhi = (x < 113) ? -1 : (((x - 113) / 48) > 15 ? 15 : (x - 113) / 48);
    const _Float16* tn = tiles + (size_t)n * P_CNT * TILE_HALVES;

    // zero slot
    if (tid < 8) ((u4*)&Ls[ZOFF])[tid] = (u4){0u, 0u, 0u, 0u};
    // stage 96 rows x 8 u4 chunks = 768 chunks
    for (int c = tid; c < LROWS * 8; c += 256) {
        const int rid = c >> 3, w = c & 7;
        const int k3 = rid >> 5, rem = rid & 31, bww = rem >> 1, pjj = rem & 1;
        const int bhh = bhlo + k3;
        u4 val = (u4){0u, 0u, 0u, 0u};
        if (bhh <= bhhi) {
            const int ti = x - 113 - 48 * bhh;       // 0..126
            const int pii = ti & 1, uu = ti >> 1;
            const int base = (pii ? (8192 + pjj * 4032) : (pjj * 4096)) + uu * 64;
            val = *(const u4*)(tn + (size_t)(bww * 16 + bhh) * TILE_HALVES
                               + base + w * 8);
        }
        *(u4*)&Ls[rid * 64 + w * 8] = val;
    }
    __syncthreads();

    float* outrow = out + ((size_t)n << 20) + (size_t)x * SENS;
    #pragma unroll
    for (int yb = 0; yb < 4; ++yb) {
        const int y = yb * 256 + tid;
        int bwlo = (y + 288) / 48 - 10; if (bwlo < 0) bwlo = 0;
        const int bwhi = (y < 113) ? -1 : (((y - 113) / 48) > 15 ? 15 : (y - 113) / 48);
        const int t0 = y - 113 - 48 * bwlo;
        float s = 0.0f;
        #pragma unroll
        for (int k3 = 0; k3 < 3; ++k3) {
            #pragma unroll
            for (int kw = 0; kw < 3; ++kw) {
                const int bww = bwlo + kw;
                const int tj = t0 - 48 * kw;
                const int pjj = tj & 1, vv = tj >> 1;
                int idx = k3 * 2048 + (bww * 2 + pjj) * 64 + vv;
                idx = (bww <= bwhi) ? idx : ZOFF;    // invalid -> zero slot
                s += (float)Ls[idx];
            }
        }
        outrow[y] = s;   // every pixel written (uncovered rows get exact 0)
    }
}

extern "C" void kernel_launch(void* const* d_in, const int* in_sizes, int n_in,
                              void* d_out, int out_size, void* d_ws, size_t ws_size,
                              hipStream_t stream) {
    const float* imgs = (const float*)d_in[0];
    const float* psf  = (const float*)d_in[1];
    float* out = (float*)d_out;
    _Float16* tiles = (_Float16*)d_ws;                    // 66.6 MB
    u4* kfrag = (u4*)((char*)d_ws + TILES_BYTES);         // 48.7 MB (total 115 MB)

    svconv_prep<<<dim3(P_CNT * 4), dim3(256), 0, stream>>>(psf, kfrag);
    svconv_main<<<dim3(IMG_N * P_CNT), dim3(256), 0, stream>>>(imgs, kfrag, tiles);
    svconv_gather<<<dim3(IMG_N * SENS), dim3(256), 0, stream>>>(tiles, out);
}

// Round 13
// 216.651 us; speedup vs baseline: 4.7381x; 4.7381x over previous
//
#include <hip/hip_runtime.h>

typedef _Float16 h8 __attribute__((ext_vector_type(8)));
typedef float    f4 __attribute__((ext_vector_type(4)));
typedef unsigned int u4 __attribute__((ext_vector_type(4)));

#define IMG_N 8
#define IMG_H 512
#define IMG_W 512
#define P_CNT 256
#define PSFN  64
#define SENS  1024

// fp16 tiles, parity-planar (halves):
// (0,0)@0 4096, (0,1)@4096 4096, (1,0)@8192 4032, (1,1)@12224 4032
#define TILE_HALVES 16256
#define TILES_BYTES ((size_t)IMG_N * P_CNT * TILE_HALVES * 2)   // 66,584,576

// Kfrag[p][cls][g][w]: h8 entry w = {K_cls[e = w+j-32][g]}_{j=0..7}, 16B-aligned
// by duplication.  w = t0 = 8q - m + (U0-16ut) + 32 in [0,89).
#define KW     90
#define KWB    (KW * 16)             // bytes per g-row
#define KFRAG_PER_P (4 * 33 * KW)    // 11880 entries

// BT[97 cols][40 r] fp16, col = c+32, zero-padded outside c in [0,32).
#define BT_COLS   97
#define BT_HALVES (BT_COLS * 40)

// ---------------- prep: build Kfrag fragment table (4 blocks per region) ---
__global__ __launch_bounds__(256) void svconv_prep(
    const float* __restrict__ psf, u4* __restrict__ kfrag)
{
    __shared__ float ps[PSFN * PSFN];
    __shared__ float Kc[4 * 33 * 33];      // Kc[cls][e][g], zero if invalid
    const int p = blockIdx.x >> 2, q4 = blockIdx.x & 3, tid = threadIdx.x;

    const float4* pp = (const float4*)(psf + (size_t)p * PSFN * PSFN);
    float4* pd = (float4*)ps;
    for (int i = tid; i < PSFN * PSFN / 4; i += 256) pd[i] = pp[i];
    __syncthreads();

    // K_cls[e][g] = Wp[a=2e-1+pi][b=2g-1+pj], Wp = 2x2-aggregated psf
    for (int idx = tid; idx < 4 * 33 * 33; idx += 256) {
        const int g = idx % 33, e = (idx / 33) % 33, cls = idx / 1089;
        const int pi = cls >> 1, pj = cls & 1;
        const int E = pi ? 32 : 33;
        float sv = 0.f;
        if (e < E) {
            const int a = 2 * e - 1 + pi, b = 2 * g - 1 + pj;
            #pragma unroll
            for (int du = 0; du < 2; ++du) {
                const int x = a + du;
                if ((unsigned)x < 64u) {
                    #pragma unroll
                    for (int dv = 0; dv < 2; ++dv) {
                        const int y = b + dv;
                        if ((unsigned)y < 64u) sv += ps[x * 64 + y];
                    }
                }
            }
        }
        Kc[idx] = sv;
    }
    __syncthreads();

    u4* kout = kfrag + (size_t)p * KFRAG_PER_P;
    for (int i2 = tid; i2 < KFRAG_PER_P / 4; i2 += 256) {
        const int idx = q4 * (KFRAG_PER_P / 4) + i2;
        const int w = idx % KW;
        const int g = (idx / KW) % 33;
        const int cls = idx / (KW * 33);
        h8 hv;
        #pragma unroll
        for (int j = 0; j < 8; ++j) {
            const int e = w + j - 32;
            const float v = ((unsigned)e < 33u) ? Kc[cls * 1089 + e * 33 + g] : 0.f;
            hv[j] = (_Float16)v;
        }
        kout[idx] = __builtin_bit_cast(u4, hv);
    }
}

// ---------------- main: MFMA, global A, LDS B; vt-split (2 blocks per n,p) -
// R12 lesson: unified VGPR+AGPR file -> acc(64) can't fit a 64-reg budget;
// never force occupancy via launch_bounds.  Instead halve per-wave work:
// block handles vhalf (vt in {2*vhalf, 2*vhalf+1}), acc = 4x2 (32 AGPR).
__global__ __launch_bounds__(256, 4) void svconv_main(
    const float* __restrict__ imgs, const u4* __restrict__ kfrag,
    _Float16* __restrict__ tiles)
{
    __shared__ __align__(16) _Float16 BT[BT_HALVES];   // 7760 B

    const int bid = blockIdx.x;
    const int vhalf = bid & 1;
    const int p = (bid >> 1) & 255;
    const int n = bid >> 9;
    const int bh = p & 15, bw = p >> 4;
    const int tid = threadIdx.x;
    const int wv = tid >> 6, lane = tid & 63;
    const int m = lane & 15, q = lane >> 4;

    for (int i = tid; i < BT_HALVES; i += 256) BT[i] = (_Float16)0.f;
    __syncthreads();
    {
        const int r0 = tid >> 5, c = tid & 31;
        const float* src = imgs + ((size_t)n * IMG_H + bh * 32) * IMG_W + bw * 32;
        for (int r = r0; r < 32; r += 8)
            BT[(c + 32) * 40 + r] = (_Float16)src[r * IMG_W + c];
    }
    __syncthreads();

    const int cls = wv, pi = cls >> 1, pj = cls & 1;
    const int U0 = pi ? 31 : 32;
    const char* btc = (const char*)BT + pj * 80;   // pj: c = v+g-32+pj

    int boff[2];
    #pragma unroll
    for (int vtl = 0; vtl < 2; ++vtl)
        boff[vtl] = (16 * (2 * vhalf + vtl) + m) * 80 + q * 16;

    const char* ka[4];
    {
        const char* base = (const char*)(kfrag + (size_t)p * KFRAG_PER_P
                                         + cls * 33 * KW);
        #pragma unroll
        for (int ut = 0; ut < 4; ++ut) {
            const int t0 = 8 * q - m + (U0 - 16 * ut) + 32;   // in [0,88]
            ka[ut] = base + t0 * 16;
        }
    }

    f4 acc[4][2];
    #pragma unroll
    for (int ut = 0; ut < 4; ++ut)
        #pragma unroll
        for (int vtl = 0; vtl < 2; ++vtl) acc[ut][vtl] = (f4){0.f, 0.f, 0.f, 0.f};

    #pragma unroll 3
    for (int g = 0; g < 33; ++g) {
        h8 A[4];
        #pragma unroll
        for (int ut = 0; ut < 4; ++ut)
            A[ut] = __builtin_bit_cast(h8, *(const u4*)(ka[ut] + g * KWB));
        h8 B[2];
        #pragma unroll
        for (int vtl = 0; vtl < 2; ++vtl)
            B[vtl] = *(const h8*)(btc + boff[vtl] + g * 80);
        #pragma unroll
        for (int ut = 0; ut < 4; ++ut)
            #pragma unroll
            for (int vtl = 0; vtl < 2; ++vtl)
                acc[ut][vtl] = __builtin_amdgcn_mfma_f32_16x16x32_f16(
                    A[ut], B[vtl], acc[ut][vtl], 0, 0, 0);
    }

    // epilogue: C/D col=lane&15 (v), row=quad*4+reg (u); fp16 planar tile
    _Float16* tile = tiles + (size_t)(n * P_CNT + p) * TILE_HALVES;
    const int plane = pi ? (8192 + pj * 4032) : (pj * 4096);
    #pragma unroll
    for (int ut = 0; ut < 4; ++ut) {
        #pragma unroll
        for (int reg = 0; reg < 4; ++reg) {
            const int u = 16 * ut + 4 * q + reg;
            if (pi == 0 || u < 63) {                 // pi=1 u=63 -> i=127 discard
                _Float16* rp = tile + plane + u * 64 + m;
                #pragma unroll
                for (int vtl = 0; vtl < 2; ++vtl)
                    rp[16 * (2 * vhalf + vtl)] = (_Float16)acc[ut][vtl][reg];
            }
        }
    }
}

// ---------------- gather: LDS-staged tile rows, XCD-swizzled ---------------
// Ls[k3][bww][pj][64] halves, k3 = bh - bhlo in [0,3); + 64-half zero slot.
#define LROWS 96
#define ZOFF  (LROWS * 64)   // 6144

__global__ __launch_bounds__(256) void svconv_gather(
    const _Float16* __restrict__ tiles, float* __restrict__ out)
{
    __shared__ __align__(16) _Float16 Ls[ZOFF + 64];

    // XCD swizzle: consecutive blocks on one XCD share n, consecutive x
    const int bid = blockIdx.x;
    const int n = bid & 7, x = bid >> 3;
    const int tid = threadIdx.x;

    int bhlo = (x + 288) / 48 - 10; if (bhlo < 0) bhlo = 0;
    const int bhhi = (x < 113) ? -1 : (((x - 113) / 48) > 15 ? 15 : (x - 113) / 48);
    const _Float16* tn = tiles + (size_t)n * P_CNT * TILE_HALVES;

    if (tid < 8) ((u4*)&Ls[ZOFF])[tid] = (u4){0u, 0u, 0u, 0u};
    for (int c = tid; c < LROWS * 8; c += 256) {
        const int rid = c >> 3, w = c & 7;
        const int k3 = rid >> 5, rem = rid & 31, bww = rem >> 1, pjj = rem & 1;
        const int bhh = bhlo + k3;
        u4 val = (u4){0u, 0u, 0u, 0u};
        if (bhh <= bhhi) {
            const int ti = x - 113 - 48 * bhh;       // 0..126
            const int pii = ti & 1, uu = ti >> 1;
            const int base = (pii ? (8192 + pjj * 4032) : (pjj * 4096)) + uu * 64;
            val = *(const u4*)(tn + (size_t)(bww * 16 + bhh) * TILE_HALVES
                               + base + w * 8);
        }
        *(u4*)&Ls[rid * 64 + w * 8] = val;
    }
    __syncthreads();

    float* outrow = out + ((size_t)n << 20) + (size_t)x * SENS;
    #pragma unroll
    for (int yb = 0; yb < 4; ++yb) {
        const int y = yb * 256 + tid;
        int bwlo = (y + 288) / 48 - 10; if (bwlo < 0) bwlo = 0;
        const int bwhi = (y < 113) ? -1 : (((y - 113) / 48) > 15 ? 15 : (y - 113) / 48);
        const int t0 = y - 113 - 48 * bwlo;
        float s = 0.0f;
        #pragma unroll
        for (int k3 = 0; k3 < 3; ++k3) {
            #pragma unroll
            for (int kw = 0; kw < 3; ++kw) {
                const int bww = bwlo + kw;
                const int tj = t0 - 48 * kw;
                const int pjj = tj & 1, vv = tj >> 1;
                int idx = k3 * 2048 + (bww * 2 + pjj) * 64 + vv;
                idx = (bww <= bwhi) ? idx : ZOFF;    // invalid -> zero slot
                s += (float)Ls[idx];
            }
        }
        outrow[y] = s;   // every pixel written (uncovered rows get exact 0)
    }
}

extern "C" void kernel_launch(void* const* d_in, const int* in_sizes, int n_in,
                              void* d_out, int out_size, void* d_ws, size_t ws_size,
                              hipStream_t stream) {
    const float* imgs = (const float*)d_in[0];
    const float* psf  = (const float*)d_in[1];
    float* out = (float*)d_out;
    _Float16* tiles = (_Float16*)d_ws;                    // 66.6 MB
    u4* kfrag = (u4*)((char*)d_ws + TILES_BYTES);         // 48.7 MB (total 115 MB)

    svconv_prep<<<dim3(P_CNT * 4), dim3(256), 0, stream>>>(psf, kfrag);
    svconv_main<<<dim3(IMG_N * P_CNT * 2), dim3(256), 0, stream>>>(imgs, kfrag, tiles);
    svconv_gather<<<dim3(IMG_N * SENS), dim3(256), 0, stream>>>(tiles, out);
}

// Round 14
// 206.668 us; speedup vs baseline: 4.9670x; 1.0483x over previous
//
#include <hip/hip_runtime.h>

typedef _Float16 h8 __attribute__((ext_vector_type(8)));
typedef float    f4 __attribute__((ext_vector_type(4)));
typedef unsigned int u4 __attribute__((ext_vector_type(4)));

#define IMG_N 8
#define IMG_H 512
#define IMG_W 512
#define P_CNT 256
#define PSFN  64
#define SENS  1024

// fp16 tiles, ROW-MAJOR [i][j]: i = 2u+pi (0..127, row 127 pad), j = 2v+pj
// (0..127, col 127 pad).  Row stride 128 halves.
#define TILE_HALVES 16384
#define TILES_BYTES ((size_t)IMG_N * P_CNT * TILE_HALVES * 2)   // 67,108,864

// Kfrag[p][cls][g][w]: h8 entry w = {K_cls[e = w+j-32][g]}_{j=0..7}, 16B-aligned
// by duplication.  w = t0 = 8q - m + (U0-16ut) + 32 in [0,89).
#define KW     90
#define KWB    (KW * 16)             // bytes per g-row
#define KFRAG_PER_P (4 * 33 * KW)    // 11880 entries

// BT[97 cols][40 r] fp16, col = c+32, zero-padded outside c in [0,32).
#define BT_COLS   97
#define BT_HALVES (BT_COLS * 40)

// ---------------- prep: build Kfrag fragment table (4 blocks per region) ---
__global__ __launch_bounds__(256) void svconv_prep(
    const float* __restrict__ psf, u4* __restrict__ kfrag)
{
    __shared__ float ps[PSFN * PSFN];
    __shared__ float Kc[4 * 33 * 33];      // Kc[cls][e][g], zero if invalid
    const int p = blockIdx.x >> 2, q4 = blockIdx.x & 3, tid = threadIdx.x;

    const float4* pp = (const float4*)(psf + (size_t)p * PSFN * PSFN);
    float4* pd = (float4*)ps;
    for (int i = tid; i < PSFN * PSFN / 4; i += 256) pd[i] = pp[i];
    __syncthreads();

    // K_cls[e][g] = Wp[a=2e-1+pi][b=2g-1+pj], Wp = 2x2-aggregated psf
    for (int idx = tid; idx < 4 * 33 * 33; idx += 256) {
        const int g = idx % 33, e = (idx / 33) % 33, cls = idx / 1089;
        const int pi = cls >> 1, pj = cls & 1;
        const int E = pi ? 32 : 33;
        float sv = 0.f;
        if (e < E) {
            const int a = 2 * e - 1 + pi, b = 2 * g - 1 + pj;
            #pragma unroll
            for (int du = 0; du < 2; ++du) {
                const int x = a + du;
                if ((unsigned)x < 64u) {
                    #pragma unroll
                    for (int dv = 0; dv < 2; ++dv) {
                        const int y = b + dv;
                        if ((unsigned)y < 64u) sv += ps[x * 64 + y];
                    }
                }
            }
        }
        Kc[idx] = sv;
    }
    __syncthreads();

    u4* kout = kfrag + (size_t)p * KFRAG_PER_P;
    for (int i2 = tid; i2 < KFRAG_PER_P / 4; i2 += 256) {
        const int idx = q4 * (KFRAG_PER_P / 4) + i2;
        const int w = idx % KW;
        const int g = (idx / KW) % 33;
        const int cls = idx / (KW * 33);
        h8 hv;
        #pragma unroll
        for (int j = 0; j < 8; ++j) {
            const int e = w + j - 32;
            const float v = ((unsigned)e < 33u) ? Kc[cls * 1089 + e * 33 + g] : 0.f;
            hv[j] = (_Float16)v;
        }
        kout[idx] = __builtin_bit_cast(u4, hv);
    }
}

// ---------------- main: R10-proven body (acc 4x4, A-traffic 1x) -----------
__global__ __launch_bounds__(256, 4) void svconv_main(
    const float* __restrict__ imgs, const u4* __restrict__ kfrag,
    _Float16* __restrict__ tiles)
{
    __shared__ __align__(16) _Float16 BT[BT_HALVES];   // 7760 B

    const int bid = blockIdx.x;
    const int n = bid >> 8, p = bid & 255;
    const int bh = p & 15, bw = p >> 4;
    const int tid = threadIdx.x;
    const int wv = tid >> 6, lane = tid & 63;
    const int m = lane & 15, q = lane >> 4;

    for (int i = tid; i < BT_HALVES; i += 256) BT[i] = (_Float16)0.f;
    __syncthreads();
    {
        const int r0 = tid >> 5, c = tid & 31;
        const float* src = imgs + ((size_t)n * IMG_H + bh * 32) * IMG_W + bw * 32;
        for (int r = r0; r < 32; r += 8)
            BT[(c + 32) * 40 + r] = (_Float16)src[r * IMG_W + c];
    }
    __syncthreads();

    const int cls = wv, pi = cls >> 1, pj = cls & 1;
    const int U0 = pi ? 31 : 32;
    const char* btc = (const char*)BT + pj * 80;   // pj: c = v+g-32+pj

    int boff[4];
    #pragma unroll
    for (int vt = 0; vt < 4; ++vt) boff[vt] = (16 * vt + m) * 80 + q * 16;

    const char* ka[4];
    {
        const char* base = (const char*)(kfrag + (size_t)p * KFRAG_PER_P
                                         + cls * 33 * KW);
        #pragma unroll
        for (int ut = 0; ut < 4; ++ut) {
            const int t0 = 8 * q - m + (U0 - 16 * ut) + 32;   // in [0,88]
            ka[ut] = base + t0 * 16;
        }
    }

    f4 acc[4][4];
    #pragma unroll
    for (int ut = 0; ut < 4; ++ut)
        #pragma unroll
        for (int vt = 0; vt < 4; ++vt) acc[ut][vt] = (f4){0.f, 0.f, 0.f, 0.f};

    #pragma unroll 3
    for (int g = 0; g < 33; ++g) {
        h8 A[4];
        #pragma unroll
        for (int ut = 0; ut < 4; ++ut)
            A[ut] = __builtin_bit_cast(h8, *(const u4*)(ka[ut] + g * KWB));
        h8 B[4];
        #pragma unroll
        for (int vt = 0; vt < 4; ++vt)
            B[vt] = *(const h8*)(btc + boff[vt] + g * 80);
        #pragma unroll
        for (int ut = 0; ut < 4; ++ut)
            #pragma unroll
            for (int vt = 0; vt < 4; ++vt)
                acc[ut][vt] = __builtin_amdgcn_mfma_f32_16x16x32_f16(
                    A[ut], B[vt], acc[ut][vt], 0, 0, 0);
    }

    // epilogue: row-major [i][j]: i = 2u+pi, j = 2v+pj (rows/cols 127 = pad)
    _Float16* tile = tiles + (size_t)(n * P_CNT + p) * TILE_HALVES;
    #pragma unroll
    for (int ut = 0; ut < 4; ++ut) {
        #pragma unroll
        for (int reg = 0; reg < 4; ++reg) {
            const int u = 16 * ut + 4 * q + reg;
            _Float16* rp = tile + (2 * u + pi) * 128 + 2 * m + pj;
            #pragma unroll
            for (int vt = 0; vt < 4; ++vt)
                rp[32 * vt] = (_Float16)acc[ut][vt][reg];
        }
    }
}

// ---------------- gather: paired-y u32 LDS reads, XCD-swizzled -------------
// Ls[k3(3)][bww(16)][136]: position j holds tile[ti(k3)][j] of region (bww,bhh);
// stride 136 halves (272 B, 16B-aligned rows); tail 128..135 zero; + zero slot.
#define LSTRIDE 136
#define ZOFF    (48 * LSTRIDE)   // 6528

__global__ __launch_bounds__(256) void svconv_gather(
    const _Float16* __restrict__ tiles, float* __restrict__ out)
{
    __shared__ __align__(16) _Float16 Ls[ZOFF + 8];

    const int bid = blockIdx.x;
    const int n = bid & 7, x = bid >> 3;        // XCD swizzle
    const int tid = threadIdx.x;

    int bhlo = (x + 288) / 48 - 10; if (bhlo < 0) bhlo = 0;
    const int bhhi = (x < 113) ? -1 : (((x - 113) / 48) > 15 ? 15 : (x - 113) / 48);
    const _Float16* tn = tiles + (size_t)n * P_CNT * TILE_HALVES;

    for (int i = tid; i < (ZOFF + 8) / 8; i += 256)
        ((u4*)Ls)[i] = (u4){0u, 0u, 0u, 0u};
    __syncthreads();

    // stage: 48 rows x 16 u4 chunks (contiguous 256B per tile row)
    for (int c = tid; c < 768; c += 256) {
        const int w = c & 15, rid = c >> 4;
        const int k3 = rid >> 4, bww = rid & 15;
        const int bhh = bhlo + k3;
        if (bhh <= bhhi) {
            const int ti = x - 113 - 48 * bhh;   // 0..126
            const u4 val = *(const u4*)(tn + (size_t)(bww * 16 + bhh) * TILE_HALVES
                                        + ti * 128 + 8 * w);
            *(u4*)&Ls[rid * LSTRIDE + 8 * w] = val;
        }
    }
    __syncthreads();

    float* outrow = out + ((size_t)n << 20) + (size_t)x * SENS;
    if (tid == 0) outrow[0] = 0.f;               // y=0 provably uncovered
    #pragma unroll
    for (int hf = 0; hf < 2; ++hf) {
        const int k = tid + 256 * hf;            // pair k: y = (2k+1, 2k+2)
        const int y0 = 2 * k + 1, y1 = y0 + 1;
        int bwlo0 = (y0 + 288) / 48 - 10; if (bwlo0 < 0) bwlo0 = 0;
        const int bwhi0 = (y0 < 113) ? -1
                          : (((y0 - 113) / 48) > 15 ? 15 : (y0 - 113) / 48);
        int bwlo1 = (y1 + 288) / 48 - 10; if (bwlo1 < 0) bwlo1 = 0;
        const int bwhi1 = (y1 < 113 || y1 > 1023) ? -1
                          : (((y1 - 113) / 48) > 15 ? 15 : (y1 - 113) / 48);
        float s0 = 0.f, s1 = 0.f;
        #pragma unroll
        for (int kw = 0; kw < 4; ++kw) {
            const int bww = bwlo0 + kw;
            const bool ok0 = (bww <= bwhi0);
            const bool ok1 = (bww >= bwlo1) && (bww <= bwhi1);
            const int tj0 = y0 - 113 - 48 * bww;        // even; in [0,126] if ok
            const int colbase = bww * LSTRIDE + tj0;
            #pragma unroll
            for (int k3 = 0; k3 < 3; ++k3) {
                const int idx = (ok0 | ok1) ? (k3 * 16 * LSTRIDE + colbase) : ZOFF;
                const unsigned v = *(const unsigned*)&Ls[idx];   // aligned u32
                const float f0 = (float)__builtin_bit_cast(
                    _Float16, (unsigned short)(v & 0xffffu));
                const float f1 = (float)__builtin_bit_cast(
                    _Float16, (unsigned short)(v >> 16));
                s0 += ok0 ? f0 : 0.f;
                s1 += ok1 ? f1 : 0.f;
            }
        }
        outrow[y0] = s0;
        if (y1 <= 1023) outrow[y1] = s1;
    }
}

extern "C" void kernel_launch(void* const* d_in, const int* in_sizes, int n_in,
                              void* d_out, int out_size, void* d_ws, size_t ws_size,
                              hipStream_t stream) {
    const float* imgs = (const float*)d_in[0];
    const float* psf  = (const float*)d_in[1];
    float* out = (float*)d_out;
    _Float16* tiles = (_Float16*)d_ws;                    // 67.1 MB
    u4* kfrag = (u4*)((char*)d_ws + TILES_BYTES);         // 48.7 MB (total 115.8 MB)

    svconv_prep<<<dim3(P_CNT * 4), dim3(256), 0, stream>>>(psf, kfrag);
    svconv_main<<<dim3(IMG_N * P_CNT), dim3(256), 0, stream>>>(imgs, kfrag, tiles);
    svconv_gather<<<dim3(IMG_N * SENS), dim3(256), 0, stream>>>(tiles, out);
}

// Round 15
// 205.213 us; speedup vs baseline: 5.0022x; 1.0071x over previous
//
#include <hip/hip_runtime.h>

typedef _Float16 h8 __attribute__((ext_vector_type(8)));
typedef float    f4 __attribute__((ext_vector_type(4)));
typedef unsigned int u4 __attribute__((ext_vector_type(4)));

#define IMG_N 8
#define IMG_H 512
#define IMG_W 512
#define P_CNT 256
#define PSFN  64
#define SENS  1024

// G: output-row-major intermediate.  G[n][x'][k][bw][128] fp16, x' = 48*bh+i
// in [0,846], k = bh - bhlo(x) in [0,3).  One (n,x) gather block reads a
// CONTIGUOUS 3*16*128*2 = 12288 B.  j=127 column is an exact 0 (conv cols in
// BT zero-pad), so paired u32 reads need no high-half mask.
#define XROWS 847
#define G_HALVES ((size_t)IMG_N * XROWS * 3 * 2048)
#define G_BYTES  (G_HALVES * 2)                     // 83,263,488

// Kfrag[p][cls][g][w]: h8 entry w = {K_cls[e = w+j-32][g]}_{j=0..7}, 16B-aligned
// by duplication.  w = t0 = 8q - m + (U0-16ut) + 32 in [0,89).
#define KW     90
#define KWB    (KW * 16)             // bytes per g-row
#define KFRAG_PER_P (4 * 33 * KW)    // 11880 entries

// BT[97 cols][40 r] fp16, col = c+32, zero-padded outside c in [0,32).
#define BT_COLS   97
#define BT_HALVES (BT_COLS * 40)

// ---------------- prep: build Kfrag fragment table (4 blocks per region) ---
__global__ __launch_bounds__(256) void svconv_prep(
    const float* __restrict__ psf, u4* __restrict__ kfrag)
{
    __shared__ float ps[PSFN * PSFN];
    __shared__ float Kc[4 * 33 * 33];      // Kc[cls][e][g], zero if invalid
    const int p = blockIdx.x >> 2, q4 = blockIdx.x & 3, tid = threadIdx.x;

    const float4* pp = (const float4*)(psf + (size_t)p * PSFN * PSFN);
    float4* pd = (float4*)ps;
    for (int i = tid; i < PSFN * PSFN / 4; i += 256) pd[i] = pp[i];
    __syncthreads();

    // K_cls[e][g] = Wp[a=2e-1+pi][b=2g-1+pj], Wp = 2x2-aggregated psf
    for (int idx = tid; idx < 4 * 33 * 33; idx += 256) {
        const int g = idx % 33, e = (idx / 33) % 33, cls = idx / 1089;
        const int pi = cls >> 1, pj = cls & 1;
        const int E = pi ? 32 : 33;
        float sv = 0.f;
        if (e < E) {
            const int a = 2 * e - 1 + pi, b = 2 * g - 1 + pj;
            #pragma unroll
            for (int du = 0; du < 2; ++du) {
                const int x = a + du;
                if ((unsigned)x < 64u) {
                    #pragma unroll
                    for (int dv = 0; dv < 2; ++dv) {
                        const int y = b + dv;
                        if ((unsigned)y < 64u) sv += ps[x * 64 + y];
                    }
                }
            }
        }
        Kc[idx] = sv;
    }
    __syncthreads();

    u4* kout = kfrag + (size_t)p * KFRAG_PER_P;
    for (int i2 = tid; i2 < KFRAG_PER_P / 4; i2 += 256) {
        const int idx = q4 * (KFRAG_PER_P / 4) + i2;
        const int w = idx % KW;
        const int g = (idx / KW) % 33;
        const int cls = idx / (KW * 33);
        h8 hv;
        #pragma unroll
        for (int j = 0; j < 8; ++j) {
            const int e = w + j - 32;
            const float v = ((unsigned)e < 33u) ? Kc[cls * 1089 + e * 33 + g] : 0.f;
            hv[j] = (_Float16)v;
        }
        kout[idx] = __builtin_bit_cast(u4, hv);
    }
}

// ---------------- main: R10/R14-proven body; epilogue -> G layout ----------
__global__ __launch_bounds__(256, 4) void svconv_main(
    const float* __restrict__ imgs, const u4* __restrict__ kfrag,
    _Float16* __restrict__ G)
{
    __shared__ __align__(16) _Float16 BT[BT_HALVES];   // 7760 B

    const int bid = blockIdx.x;
    const int n = bid >> 8, p = bid & 255;
    const int bh = p & 15, bw = p >> 4;
    const int tid = threadIdx.x;
    const int wv = tid >> 6, lane = tid & 63;
    const int m = lane & 15, q = lane >> 4;

    for (int i = tid; i < BT_HALVES; i += 256) BT[i] = (_Float16)0.f;
    __syncthreads();
    {
        const int r0 = tid >> 5, c = tid & 31;
        const float* src = imgs + ((size_t)n * IMG_H + bh * 32) * IMG_W + bw * 32;
        for (int r = r0; r < 32; r += 8)
            BT[(c + 32) * 40 + r] = (_Float16)src[r * IMG_W + c];
    }
    __syncthreads();

    const int cls = wv, pi = cls >> 1, pj = cls & 1;
    const int U0 = pi ? 31 : 32;
    const char* btc = (const char*)BT + pj * 80;   // pj: c = v+g-32+pj

    int boff[4];
    #pragma unroll
    for (int vt = 0; vt < 4; ++vt) boff[vt] = (16 * vt + m) * 80 + q * 16;

    const char* ka[4];
    {
        const char* base = (const char*)(kfrag + (size_t)p * KFRAG_PER_P
                                         + cls * 33 * KW);
        #pragma unroll
        for (int ut = 0; ut < 4; ++ut) {
            const int t0 = 8 * q - m + (U0 - 16 * ut) + 32;   // in [0,88]
            ka[ut] = base + t0 * 16;
        }
    }

    f4 acc[4][4];
    #pragma unroll
    for (int ut = 0; ut < 4; ++ut)
        #pragma unroll
        for (int vt = 0; vt < 4; ++vt) acc[ut][vt] = (f4){0.f, 0.f, 0.f, 0.f};

    #pragma unroll 3
    for (int g = 0; g < 33; ++g) {
        h8 A[4];
        #pragma unroll
        for (int ut = 0; ut < 4; ++ut)
            A[ut] = __builtin_bit_cast(h8, *(const u4*)(ka[ut] + g * KWB));
        h8 B[4];
        #pragma unroll
        for (int vt = 0; vt < 4; ++vt)
            B[vt] = *(const h8*)(btc + boff[vt] + g * 80);
        #pragma unroll
        for (int ut = 0; ut < 4; ++ut)
            #pragma unroll
            for (int vt = 0; vt < 4; ++vt)
                acc[ut][vt] = __builtin_amdgcn_mfma_f32_16x16x32_f16(
                    A[ut], B[vt], acc[ut][vt], 0, 0, 0);
    }

    // epilogue: i = 2u+pi (skip i=127 pad row), x' = 48*bh+i,
    // k = bh - bhlo(x) = min(bh, 2 - (i+17)/48)  [verified bijective]
    _Float16* Gn = G + (size_t)n * XROWS * 3 * 2048;
    #pragma unroll
    for (int ut = 0; ut < 4; ++ut) {
        #pragma unroll
        for (int reg = 0; reg < 4; ++reg) {
            const int u = 16 * ut + 4 * q + reg;
            const int i = 2 * u + pi;
            if (i < 127) {
                const int d = (i + 17) / 48;                  // 0,1,2
                const int k = (bh < 2 - d) ? bh : (2 - d);
                _Float16* rp = Gn + ((size_t)(48 * bh + i) * 3 + k) * 2048
                               + bw * 128 + 2 * m + pj;
                #pragma unroll
                for (int vt = 0; vt < 4; ++vt)
                    rp[32 * vt] = (_Float16)acc[ut][vt][reg];
            }
        }
    }
}

// ---------------- gather: contiguous 12 KB stage, paired-y u32 reads -------
#define ZOFF (3 * 2048)   // zero slot

__global__ __launch_bounds__(256) void svconv_gather(
    const _Float16* __restrict__ G, float* __restrict__ out)
{
    __shared__ __align__(16) _Float16 Ls[ZOFF + 8];

    const int bid = blockIdx.x;
    const int n = bid & 7, x = bid >> 3;        // XCD swizzle
    const int tid = threadIdx.x;

    int bhlo = (x + 288) / 48 - 10; if (bhlo < 0) bhlo = 0;
    const int bhhi = (x < 113) ? -1 : (((x - 113) / 48) > 15 ? 15 : (x - 113) / 48);
    const int nvalid = bhhi - bhlo + 1;          // may be <= 0
    const int xp = x - 113;

    if (tid == 0) *(u4*)&Ls[ZOFF] = (u4){0u, 0u, 0u, 0u};
    const u4* Gb = (const u4*)(G + ((size_t)n * XROWS + xp) * 3 * 2048);
    #pragma unroll
    for (int k3 = 0; k3 < 3; ++k3) {             // 256 u4 per k slot, contiguous
        u4 val = (u4){0u, 0u, 0u, 0u};
        if ((unsigned)xp < (unsigned)XROWS && k3 < nvalid)
            val = Gb[k3 * 256 + tid];            // poison k's never loaded
        *(u4*)&Ls[(k3 * 256 + tid) * 8] = val;
    }
    __syncthreads();

    float* outrow = out + ((size_t)n << 20) + (size_t)x * SENS;
    if (tid == 0) outrow[0] = 0.f;               // y=0 provably uncovered
    #pragma unroll
    for (int hf = 0; hf < 2; ++hf) {
        const int k = tid + 256 * hf;            // pair: y = (2k+1, 2k+2)
        const int y0 = 2 * k + 1, y1 = y0 + 1;
        int bwlo0 = (y0 + 288) / 48 - 10; if (bwlo0 < 0) bwlo0 = 0;
        const int bwhi0 = (y0 < 113) ? -1
                          : (((y0 - 113) / 48) > 15 ? 15 : (y0 - 113) / 48);
        int bwlo1 = (y1 + 288) / 48 - 10; if (bwlo1 < 0) bwlo1 = 0;
        const int bwhi1 = (y1 < 113 || y1 > 1023) ? -1
                          : (((y1 - 113) / 48) > 15 ? 15 : (y1 - 113) / 48);
        float s0 = 0.f, s1 = 0.f;
        #pragma unroll
        for (int kw = 0; kw < 4; ++kw) {
            const int bww = bwlo0 + kw;
            const bool ok0 = (bww <= bwhi0);
            const bool ok1 = (bww >= bwlo1) && (bww <= bwhi1);
            const int tj0 = y0 - 113 - 48 * bww; // even & >=0 whenever ok0|ok1
            const int colbase = bww * 128 + tj0;
            #pragma unroll
            for (int k3 = 0; k3 < 3; ++k3) {
                const int idx = (ok0 | ok1) ? (k3 * 2048 + colbase) : ZOFF;
                const unsigned v = *(const unsigned*)&Ls[idx];   // aligned u32
                const float f0 = (float)__builtin_bit_cast(
                    _Float16, (unsigned short)(v & 0xffffu));
                const float f1 = (float)__builtin_bit_cast(
                    _Float16, (unsigned short)(v >> 16));
                s0 += ok0 ? f0 : 0.f;
                s1 += ok1 ? f1 : 0.f;            // tj0+1==127 reads exact 0
            }
        }
        outrow[y0] = s0;
        if (y1 <= 1023) outrow[y1] = s1;
    }
}

extern "C" void kernel_launch(void* const* d_in, const int* in_sizes, int n_in,
                              void* d_out, int out_size, void* d_ws, size_t ws_size,
                              hipStream_t stream) {
    const float* imgs = (const float*)d_in[0];
    const float* psf  = (const float*)d_in[1];
    float* out = (float*)d_out;
    _Float16* G = (_Float16*)d_ws;                        // 83.3 MB
    u4* kfrag = (u4*)((char*)d_ws + G_BYTES);             // 48.7 MB (131.9 MB total)

    svconv_prep<<<dim3(P_CNT * 4), dim3(256), 0, stream>>>(psf, kfrag);
    svconv_main<<<dim3(IMG_N * P_CNT), dim3(256), 0, stream>>>(imgs, kfrag, G);
    svconv_gather<<<dim3(IMG_N * SENS), dim3(256), 0, stream>>>(G, out);
}